// Round 1
// baseline (4631.732 us; speedup 1.0000x reference)
//
#include <hip/hip_runtime.h>

#define N_NODES  50000
#define N_EDGES  800000
#define N_GRAPHS 128
#define DIM      128
#define CLS      10

// ---------------- degree / counts ----------------
__global__ __launch_bounds__(256) void k_deg(const int* __restrict__ dst, float* __restrict__ deg) {
    int i = blockIdx.x * 256 + threadIdx.x;
    if (i < N_EDGES) atomicAdd(&deg[dst[i]], 1.0f);
}

__global__ __launch_bounds__(256) void k_count(const int* __restrict__ gid, float* __restrict__ counts) {
    int i = blockIdx.x * 256 + threadIdx.x;
    if (i < N_NODES) atomicAdd(&counts[gid[i]], 1.0f);
}

// deg -> 1/max(deg,1) in place
__global__ __launch_bounds__(256) void k_invdeg(float* __restrict__ deg) {
    int i = blockIdx.x * 256 + threadIdx.x;
    if (i < N_NODES) deg[i] = 1.0f / fmaxf(deg[i], 1.0f);
}

// ---------------- edge scatter: msg[dst] += h[src] ----------------
// one thread = (edge, float4 chunk); 32 chunks per edge row of 128 floats
__global__ __launch_bounds__(256) void k_scatter(const float* __restrict__ h,
                                                 const int* __restrict__ src,
                                                 const int* __restrict__ dst,
                                                 float* __restrict__ msg) {
    unsigned tid = blockIdx.x * 256u + threadIdx.x;
    unsigned e = tid >> 5;
    unsigned c = tid & 31u;
    if (e >= N_EDGES) return;
    int s = src[e], d = dst[e];
    float4 v = ((const float4*)(h + (size_t)s * DIM))[c];
    float* p = msg + (size_t)d * DIM + c * 4;
    atomicAdd(p + 0, v.x);
    atomicAdd(p + 1, v.y);
    atomicAdd(p + 2, v.z);
    atomicAdd(p + 3, v.w);
}

// ---------------- fused SAGE layer ----------------
// hout = relu(hin @ Ws + (msg * invdeg) @ Wn + b)
// block: 256 threads, 64 (M) x 128 (N) tile, K chunks of 32, two passes (self/neigh)
__global__ __launch_bounds__(256) void k_sage(const float* __restrict__ hin,
                                              const float* __restrict__ msg,
                                              const float* __restrict__ invdeg,
                                              const float* __restrict__ Ws,
                                              const float* __restrict__ Wn,
                                              const float* __restrict__ bias,
                                              float* __restrict__ hout) {
    __shared__ float As[64][33];   // +1 pad: scalar a-reads conflict-free
    __shared__ float Bs[32][128];  // float4-read, row-broadcast across lanes

    const int tid  = threadIdx.x;
    const int m0   = blockIdx.x * 64;
    const int col0 = (tid & 15) * 8;   // 16 col-groups x 8
    const int row0 = (tid >> 4) * 4;   // 16 row-groups x 4

    float acc[4][8];
#pragma unroll
    for (int i = 0; i < 4; ++i)
#pragma unroll
        for (int j = 0; j < 8; ++j) acc[i][j] = 0.f;

    for (int pass = 0; pass < 2; ++pass) {
        const float* __restrict__ A = pass ? msg : hin;
        const float* __restrict__ W = pass ? Wn : Ws;
        for (int kt = 0; kt < 4; ++kt) {
            const int k0 = kt * 32;
            // stage A tile: 64x32 floats (2 float4 per thread), scaled by invdeg on pass 1
#pragma unroll
            for (int c = tid; c < 512; c += 256) {
                int r = c >> 3, kq = c & 7;
                int m = m0 + r;
                float4 v = make_float4(0.f, 0.f, 0.f, 0.f);
                float s = 1.0f;
                if (m < N_NODES) {
                    v = *(const float4*)(A + (size_t)m * DIM + k0 + kq * 4);
                    if (pass) s = invdeg[m];
                }
                As[r][kq * 4 + 0] = v.x * s;
                As[r][kq * 4 + 1] = v.y * s;
                As[r][kq * 4 + 2] = v.z * s;
                As[r][kq * 4 + 3] = v.w * s;
            }
            // stage B tile: 32x128 floats (4 float4 per thread)
#pragma unroll
            for (int c = tid; c < 1024; c += 256) {
                int r = c >> 5, cq = c & 31;
                *(float4*)&Bs[r][cq * 4] = *(const float4*)(W + (size_t)(k0 + r) * DIM + cq * 4);
            }
            __syncthreads();
#pragma unroll
            for (int kk = 0; kk < 32; ++kk) {
                float a[4];
#pragma unroll
                for (int i = 0; i < 4; ++i) a[i] = As[row0 + i][kk];
                float4 b0 = *(const float4*)&Bs[kk][col0];
                float4 b1 = *(const float4*)&Bs[kk][col0 + 4];
                float bb[8] = {b0.x, b0.y, b0.z, b0.w, b1.x, b1.y, b1.z, b1.w};
#pragma unroll
                for (int i = 0; i < 4; ++i)
#pragma unroll
                    for (int j = 0; j < 8; ++j) acc[i][j] += a[i] * bb[j];
            }
            __syncthreads();
        }
    }
    // epilogue: bias + relu, float4 stores
#pragma unroll
    for (int i = 0; i < 4; ++i) {
        int m = m0 + row0 + i;
        if (m < N_NODES) {
            float4 o0, o1;
            o0.x = fmaxf(acc[i][0] + bias[col0 + 0], 0.f);
            o0.y = fmaxf(acc[i][1] + bias[col0 + 1], 0.f);
            o0.z = fmaxf(acc[i][2] + bias[col0 + 2], 0.f);
            o0.w = fmaxf(acc[i][3] + bias[col0 + 3], 0.f);
            o1.x = fmaxf(acc[i][4] + bias[col0 + 4], 0.f);
            o1.y = fmaxf(acc[i][5] + bias[col0 + 5], 0.f);
            o1.z = fmaxf(acc[i][6] + bias[col0 + 6], 0.f);
            o1.w = fmaxf(acc[i][7] + bias[col0 + 7], 0.f);
            *(float4*)(hout + (size_t)m * DIM + col0)     = o0;
            *(float4*)(hout + (size_t)m * DIM + col0 + 4) = o1;
        }
    }
}

// ---------------- graph mean-pool (graph_ids sorted -> run-length accumulate) ----------------
__global__ __launch_bounds__(256) void k_pool(const float* __restrict__ h,
                                              const int* __restrict__ gid,
                                              float* __restrict__ pooled) {
    int d = threadIdx.x & 127;
    int half = threadIdx.x >> 7;
    int n0 = blockIdx.x * 128;
    float acc = 0.f;
    int cur = -1;
    for (int i = half; i < 128; i += 2) {
        int n = n0 + i;
        if (n >= N_NODES) break;
        int g = gid[n];
        if (g != cur) {
            if (cur >= 0) atomicAdd(&pooled[(size_t)cur * DIM + d], acc);
            acc = 0.f;
            cur = g;
        }
        acc += h[(size_t)n * DIM + d];
    }
    if (cur >= 0) atomicAdd(&pooled[(size_t)cur * DIM + d], acc);
}

// ---------------- classifier: out = (pooled/counts) @ Wf + bf ----------------
__global__ __launch_bounds__(256) void k_final(const float* __restrict__ pooled,
                                               const float* __restrict__ counts,
                                               const float* __restrict__ Wf,
                                               const float* __restrict__ bf,
                                               float* __restrict__ out) {
    int t = blockIdx.x * 256 + threadIdx.x;
    if (t >= N_GRAPHS * CLS) return;
    int g = t / CLS, c = t % CLS;
    float inv = 1.0f / fmaxf(counts[g], 1.0f);
    float s = 0.f;
    for (int k = 0; k < DIM; ++k) s += pooled[(size_t)g * DIM + k] * Wf[k * CLS + c];
    out[t] = s * inv + bf[c];
}

extern "C" void kernel_launch(void* const* d_in, const int* in_sizes, int n_in,
                              void* d_out, int out_size, void* d_ws, size_t ws_size,
                              hipStream_t stream) {
    const float* features = (const float*)d_in[0];
    const int*   esrc     = (const int*)d_in[1];
    const int*   edst     = (const int*)d_in[2];
    const int*   gids     = (const int*)d_in[3];
    const float* Wss[3] = {(const float*)d_in[4], (const float*)d_in[7], (const float*)d_in[10]};
    const float* Wns[3] = {(const float*)d_in[5], (const float*)d_in[8], (const float*)d_in[11]};
    const float* bs[3]  = {(const float*)d_in[6], (const float*)d_in[9], (const float*)d_in[12]};
    const float* Wf = (const float*)d_in[13];
    const float* bfv = (const float*)d_in[14];
    float* out = (float*)d_out;

    // workspace layout (floats): invdeg | msg | hA | hB | pooled | counts
    float* deg    = (float*)d_ws;                       // 50000 (becomes invdeg)
    float* msg    = deg + 50048;
    float* hA     = msg + (size_t)N_NODES * DIM;
    float* hB     = hA  + (size_t)N_NODES * DIM;
    float* pooled = hB  + (size_t)N_NODES * DIM;
    float* counts = pooled + (size_t)N_GRAPHS * DIM;
    // total ~77.1 MB

    hipMemsetAsync(deg, 0, 50048 * sizeof(float), stream);
    hipMemsetAsync(pooled, 0, (N_GRAPHS * DIM + N_GRAPHS) * sizeof(float), stream);

    k_deg<<<(N_EDGES + 255) / 256, 256, 0, stream>>>(edst, deg);
    k_count<<<(N_NODES + 255) / 256, 256, 0, stream>>>(gids, counts);
    k_invdeg<<<(N_NODES + 255) / 256, 256, 0, stream>>>(deg);

    const float* hcur = features;
    float* houts[3] = {hA, hB, hA};
    for (int l = 0; l < 3; ++l) {
        hipMemsetAsync(msg, 0, (size_t)N_NODES * DIM * sizeof(float), stream);
        k_scatter<<<(N_EDGES * 32) / 256, 256, 0, stream>>>(hcur, esrc, edst, msg);
        k_sage<<<(N_NODES + 63) / 64, 256, 0, stream>>>(hcur, msg, deg, Wss[l], Wns[l], bs[l], houts[l]);
        hcur = houts[l];
    }

    k_pool<<<(N_NODES + 127) / 128, 256, 0, stream>>>(hcur, gids, pooled);
    k_final<<<(N_GRAPHS * CLS + 255) / 256, 256, 0, stream>>>(pooled, counts, Wf, bfv, out);
}

// Round 2
// 885.828 us; speedup vs baseline: 5.2287x; 5.2287x over previous
//
#include <hip/hip_runtime.h>

#define N_NODES  50000
#define N_EDGES  800000
#define N_GRAPHS 128
#define DIM      128
#define CLS      10

// ---------------- int degree count ----------------
__global__ __launch_bounds__(256) void k_deg_i(const int* __restrict__ dst, int* __restrict__ deg) {
    int i = blockIdx.x * 256 + threadIdx.x;
    if (i < N_EDGES) atomicAdd(&deg[dst[i]], 1);
}

__global__ __launch_bounds__(256) void k_count(const int* __restrict__ gid, float* __restrict__ counts) {
    int i = blockIdx.x * 256 + threadIdx.x;
    if (i < N_NODES) atomicAdd(&counts[gid[i]], 1.0f);
}

// ---------------- single-block exclusive scan over degrees -> rowptr ----------------
// 256 threads, each owns a contiguous segment of ceil(N/256) elements.
__global__ __launch_bounds__(256) void k_scan(const int* __restrict__ deg, int* __restrict__ rowptr) {
    __shared__ int sums[256];
    const int tid = threadIdx.x;
    const int seg = (N_NODES + 255) / 256;
    const int lo = tid * seg;
    const int hi = min(lo + seg, N_NODES);
    int s = 0;
    for (int i = lo; i < hi; ++i) s += deg[i];
    sums[tid] = s;
    __syncthreads();
    // Hillis-Steele inclusive scan in LDS
    for (int off = 1; off < 256; off <<= 1) {
        int v = sums[tid];
        int add = (tid >= off) ? sums[tid - off] : 0;
        __syncthreads();
        sums[tid] = v + add;
        __syncthreads();
    }
    int running = (tid > 0) ? sums[tid - 1] : 0;
    for (int i = lo; i < hi; ++i) {
        rowptr[i] = running;
        running += deg[i];
    }
    if (tid == 255) rowptr[N_NODES] = sums[255];
}

// ---------------- CSR fill: cursor pre-loaded with rowptr ----------------
__global__ __launch_bounds__(256) void k_fill(const int* __restrict__ src, const int* __restrict__ dst,
                                              int* __restrict__ cursor, int* __restrict__ eidx) {
    int i = blockIdx.x * 256 + threadIdx.x;
    if (i < N_EDGES) {
        int pos = atomicAdd(&cursor[dst[i]], 1);
        eidx[pos] = src[i];
    }
}

// ---------------- gather aggregation: one wave per node ----------------
// msg[n] = mean over in-edges of h[src]; pre-normalized (zero-degree -> 0)
__global__ __launch_bounds__(256) void k_gather(const float* __restrict__ h,
                                                const int* __restrict__ rowptr,
                                                const int* __restrict__ eidx,
                                                float* __restrict__ msg) {
    const int wave = (blockIdx.x * 256 + threadIdx.x) >> 6;
    const int lane = threadIdx.x & 63;
    if (wave >= N_NODES) return;
    const int beg = rowptr[wave], end = rowptr[wave + 1];
    float2 acc = make_float2(0.f, 0.f);
    int j = beg;
    for (; j + 1 < end; j += 2) {  // 2 edges in flight
        int s0 = eidx[j], s1 = eidx[j + 1];
        float2 v0 = *(const float2*)(h + (size_t)s0 * DIM + lane * 2);
        float2 v1 = *(const float2*)(h + (size_t)s1 * DIM + lane * 2);
        acc.x += v0.x + v1.x;
        acc.y += v0.y + v1.y;
    }
    if (j < end) {
        int s0 = eidx[j];
        float2 v0 = *(const float2*)(h + (size_t)s0 * DIM + lane * 2);
        acc.x += v0.x;
        acc.y += v0.y;
    }
    const float inv = (end > beg) ? 1.0f / (float)(end - beg) : 0.f;
    *(float2*)(msg + (size_t)wave * DIM + lane * 2) = make_float2(acc.x * inv, acc.y * inv);
}

// ---------------- fused SAGE layer ----------------
// hout = relu(hin @ Ws + msg @ Wn + b)   (msg already mean-normalized)
__global__ __launch_bounds__(256) void k_sage(const float* __restrict__ hin,
                                              const float* __restrict__ msg,
                                              const float* __restrict__ Ws,
                                              const float* __restrict__ Wn,
                                              const float* __restrict__ bias,
                                              float* __restrict__ hout) {
    __shared__ float As[64][33];   // +1 pad: scalar a-reads conflict-free
    __shared__ float Bs[32][128];  // float4-read, row-broadcast across lanes

    const int tid  = threadIdx.x;
    const int m0   = blockIdx.x * 64;
    const int col0 = (tid & 15) * 8;   // 16 col-groups x 8
    const int row0 = (tid >> 4) * 4;   // 16 row-groups x 4

    float acc[4][8];
#pragma unroll
    for (int i = 0; i < 4; ++i)
#pragma unroll
        for (int j = 0; j < 8; ++j) acc[i][j] = 0.f;

    for (int pass = 0; pass < 2; ++pass) {
        const float* __restrict__ A = pass ? msg : hin;
        const float* __restrict__ W = pass ? Wn : Ws;
        for (int kt = 0; kt < 4; ++kt) {
            const int k0 = kt * 32;
            // stage A tile: 64x32 floats (2 float4 per thread)
#pragma unroll
            for (int c = tid; c < 512; c += 256) {
                int r = c >> 3, kq = c & 7;
                int m = m0 + r;
                float4 v = make_float4(0.f, 0.f, 0.f, 0.f);
                if (m < N_NODES) v = *(const float4*)(A + (size_t)m * DIM + k0 + kq * 4);
                As[r][kq * 4 + 0] = v.x;
                As[r][kq * 4 + 1] = v.y;
                As[r][kq * 4 + 2] = v.z;
                As[r][kq * 4 + 3] = v.w;
            }
            // stage B tile: 32x128 floats (4 float4 per thread)
#pragma unroll
            for (int c = tid; c < 1024; c += 256) {
                int r = c >> 5, cq = c & 31;
                *(float4*)&Bs[r][cq * 4] = *(const float4*)(W + (size_t)(k0 + r) * DIM + cq * 4);
            }
            __syncthreads();
#pragma unroll
            for (int kk = 0; kk < 32; ++kk) {
                float a[4];
#pragma unroll
                for (int i = 0; i < 4; ++i) a[i] = As[row0 + i][kk];
                float4 b0 = *(const float4*)&Bs[kk][col0];
                float4 b1 = *(const float4*)&Bs[kk][col0 + 4];
                float bb[8] = {b0.x, b0.y, b0.z, b0.w, b1.x, b1.y, b1.z, b1.w};
#pragma unroll
                for (int i = 0; i < 4; ++i)
#pragma unroll
                    for (int j = 0; j < 8; ++j) acc[i][j] += a[i] * bb[j];
            }
            __syncthreads();
        }
    }
    // epilogue: bias + relu, float4 stores
#pragma unroll
    for (int i = 0; i < 4; ++i) {
        int m = m0 + row0 + i;
        if (m < N_NODES) {
            float4 o0, o1;
            o0.x = fmaxf(acc[i][0] + bias[col0 + 0], 0.f);
            o0.y = fmaxf(acc[i][1] + bias[col0 + 1], 0.f);
            o0.z = fmaxf(acc[i][2] + bias[col0 + 2], 0.f);
            o0.w = fmaxf(acc[i][3] + bias[col0 + 3], 0.f);
            o1.x = fmaxf(acc[i][4] + bias[col0 + 4], 0.f);
            o1.y = fmaxf(acc[i][5] + bias[col0 + 5], 0.f);
            o1.z = fmaxf(acc[i][6] + bias[col0 + 6], 0.f);
            o1.w = fmaxf(acc[i][7] + bias[col0 + 7], 0.f);
            *(float4*)(hout + (size_t)m * DIM + col0)     = o0;
            *(float4*)(hout + (size_t)m * DIM + col0 + 4) = o1;
        }
    }
}

// ---------------- graph mean-pool (graph_ids sorted -> run-length accumulate) ----------------
__global__ __launch_bounds__(256) void k_pool(const float* __restrict__ h,
                                              const int* __restrict__ gid,
                                              float* __restrict__ pooled) {
    int d = threadIdx.x & 127;
    int half = threadIdx.x >> 7;
    int n0 = blockIdx.x * 128;
    float acc = 0.f;
    int cur = -1;
    for (int i = half; i < 128; i += 2) {
        int n = n0 + i;
        if (n >= N_NODES) break;
        int g = gid[n];
        if (g != cur) {
            if (cur >= 0) atomicAdd(&pooled[(size_t)cur * DIM + d], acc);
            acc = 0.f;
            cur = g;
        }
        acc += h[(size_t)n * DIM + d];
    }
    if (cur >= 0) atomicAdd(&pooled[(size_t)cur * DIM + d], acc);
}

// ---------------- classifier: out = (pooled/counts) @ Wf + bf ----------------
__global__ __launch_bounds__(256) void k_final(const float* __restrict__ pooled,
                                               const float* __restrict__ counts,
                                               const float* __restrict__ Wf,
                                               const float* __restrict__ bf,
                                               float* __restrict__ out) {
    int t = blockIdx.x * 256 + threadIdx.x;
    if (t >= N_GRAPHS * CLS) return;
    int g = t / CLS, c = t % CLS;
    float inv = 1.0f / fmaxf(counts[g], 1.0f);
    float s = 0.f;
    for (int k = 0; k < DIM; ++k) s += pooled[(size_t)g * DIM + k] * Wf[k * CLS + c];
    out[t] = s * inv + bf[c];
}

extern "C" void kernel_launch(void* const* d_in, const int* in_sizes, int n_in,
                              void* d_out, int out_size, void* d_ws, size_t ws_size,
                              hipStream_t stream) {
    const float* features = (const float*)d_in[0];
    const int*   esrc     = (const int*)d_in[1];
    const int*   edst     = (const int*)d_in[2];
    const int*   gids     = (const int*)d_in[3];
    const float* Wss[3] = {(const float*)d_in[4], (const float*)d_in[7], (const float*)d_in[10]};
    const float* Wns[3] = {(const float*)d_in[5], (const float*)d_in[8], (const float*)d_in[11]};
    const float* bs[3]  = {(const float*)d_in[6], (const float*)d_in[9], (const float*)d_in[12]};
    const float* Wf = (const float*)d_in[13];
    const float* bfv = (const float*)d_in[14];
    float* out = (float*)d_out;

    // workspace layout: ints first, then floats (~80.7 MB total)
    int* deg_i  = (int*)d_ws;            // 50048
    int* rowptr = deg_i + 50048;         // 50064 (50001 used)
    int* cursor = rowptr + 50064;        // 50048
    int* eidx   = cursor + 50048;        // 800000
    float* msg    = (float*)(eidx + 800000);          // 6.4M
    float* hA     = msg + (size_t)N_NODES * DIM;      // 6.4M
    float* hB     = hA  + (size_t)N_NODES * DIM;      // 6.4M
    float* pooled = hB  + (size_t)N_NODES * DIM;      // 16384
    float* counts = pooled + N_GRAPHS * DIM;          // 128

    hipMemsetAsync(deg_i, 0, 50048 * sizeof(int), stream);
    hipMemsetAsync(pooled, 0, (N_GRAPHS * DIM + N_GRAPHS) * sizeof(float), stream);

    // CSR build (edge_dst is launch-invariant; rebuilt each call per harness rules)
    k_deg_i<<<(N_EDGES + 255) / 256, 256, 0, stream>>>(edst, deg_i);
    k_count<<<(N_NODES + 255) / 256, 256, 0, stream>>>(gids, counts);
    k_scan<<<1, 256, 0, stream>>>(deg_i, rowptr);
    hipMemcpyAsync(cursor, rowptr, 50000 * sizeof(int), hipMemcpyDeviceToDevice, stream);
    k_fill<<<(N_EDGES + 255) / 256, 256, 0, stream>>>(esrc, edst, cursor, eidx);

    const float* hcur = features;
    float* houts[3] = {hA, hB, hA};
    for (int l = 0; l < 3; ++l) {
        k_gather<<<(N_NODES * 64 + 255) / 256, 256, 0, stream>>>(hcur, rowptr, eidx, msg);
        k_sage<<<(N_NODES + 63) / 64, 256, 0, stream>>>(hcur, msg, Wss[l], Wns[l], bs[l], houts[l]);
        hcur = houts[l];
    }

    k_pool<<<(N_NODES + 127) / 128, 256, 0, stream>>>(hcur, gids, pooled);
    k_final<<<(N_GRAPHS * CLS + 255) / 256, 256, 0, stream>>>(pooled, counts, Wf, bfv, out);
}

// Round 3
// 741.902 us; speedup vs baseline: 6.2431x; 1.1940x over previous
//
#include <hip/hip_runtime.h>

#define N_NODES  50000
#define N_EDGES  800000
#define N_GRAPHS 128
#define DIM      128
#define CLS      10

// ---------------- int degree count ----------------
__global__ __launch_bounds__(256) void k_deg_i(const int* __restrict__ dst, int* __restrict__ deg) {
    int i = blockIdx.x * 256 + threadIdx.x;
    if (i < N_EDGES) atomicAdd(&deg[dst[i]], 1);
}

// ---------------- graph counts via binary search (graph_ids sorted) ----------------
__global__ __launch_bounds__(128) void k_count_sorted(const int* __restrict__ gid, float* __restrict__ counts) {
    int g = threadIdx.x;  // one thread per graph, single block of 128
    int lo = 0, hi = N_NODES;
    while (lo < hi) { int mid = (lo + hi) >> 1; if (gid[mid] < g) lo = mid + 1; else hi = mid; }
    int start = lo;
    lo = 0; hi = N_NODES;
    while (lo < hi) { int mid = (lo + hi) >> 1; if (gid[mid] <= g) lo = mid + 1; else hi = mid; }
    counts[g] = (float)(lo - start);
}

// ---------------- single-block exclusive scan over degrees -> rowptr ----------------
__global__ __launch_bounds__(256) void k_scan(const int* __restrict__ deg, int* __restrict__ rowptr) {
    __shared__ int sums[256];
    const int tid = threadIdx.x;
    const int seg = (N_NODES + 255) / 256;
    const int lo = tid * seg;
    const int hi = min(lo + seg, N_NODES);
    int s = 0;
    for (int i = lo; i < hi; ++i) s += deg[i];
    sums[tid] = s;
    __syncthreads();
    for (int off = 1; off < 256; off <<= 1) {
        int v = sums[tid];
        int add = (tid >= off) ? sums[tid - off] : 0;
        __syncthreads();
        sums[tid] = v + add;
        __syncthreads();
    }
    int running = (tid > 0) ? sums[tid - 1] : 0;
    for (int i = lo; i < hi; ++i) {
        rowptr[i] = running;
        running += deg[i];
    }
    if (tid == 255) rowptr[N_NODES] = sums[255];
}

// ---------------- CSR fill: cursor pre-loaded with rowptr ----------------
__global__ __launch_bounds__(256) void k_fill(const int* __restrict__ src, const int* __restrict__ dst,
                                              int* __restrict__ cursor, int* __restrict__ eidx) {
    int i = blockIdx.x * 256 + threadIdx.x;
    if (i < N_EDGES) {
        int pos = atomicAdd(&cursor[dst[i]], 1);
        eidx[pos] = src[i];
    }
}

// ---------------- gather aggregation: one wave per node ----------------
// lane = (edge-slot lane>>5) x (dim-quad lane&31); float4 loads, shfl-combine
__global__ __launch_bounds__(256) void k_gather(const float* __restrict__ h,
                                                const int* __restrict__ rowptr,
                                                const int* __restrict__ eidx,
                                                float* __restrict__ msg) {
    const int wave = (blockIdx.x * 256 + threadIdx.x) >> 6;
    const int lane = threadIdx.x & 63;
    if (wave >= N_NODES) return;
    const int epar = lane >> 5;        // which edge of the pair
    const int d0   = (lane & 31) * 4;  // dim offset
    const int beg = rowptr[wave], end = rowptr[wave + 1];
    float4 acc = make_float4(0.f, 0.f, 0.f, 0.f);
    for (int j = beg + epar; j < end; j += 2) {
        int s = eidx[j];
        float4 v = *(const float4*)(h + (size_t)s * DIM + d0);
        acc.x += v.x; acc.y += v.y; acc.z += v.z; acc.w += v.w;
    }
    // combine the two half-wave partial sums (lanes l and l^32 hold same dims)
    acc.x += __shfl_xor(acc.x, 32);
    acc.y += __shfl_xor(acc.y, 32);
    acc.z += __shfl_xor(acc.z, 32);
    acc.w += __shfl_xor(acc.w, 32);
    if (epar == 0) {
        const float inv = (end > beg) ? 1.0f / (float)(end - beg) : 0.f;
        acc.x *= inv; acc.y *= inv; acc.z *= inv; acc.w *= inv;
        *(float4*)(msg + (size_t)wave * DIM + d0) = acc;
    }
}

// ---------------- fused SAGE layer ----------------
// hout = relu(hin @ Ws + msg @ Wn + b)   (msg already mean-normalized)
__global__ __launch_bounds__(256) void k_sage(const float* __restrict__ hin,
                                              const float* __restrict__ msg,
                                              const float* __restrict__ Ws,
                                              const float* __restrict__ Wn,
                                              const float* __restrict__ bias,
                                              float* __restrict__ hout) {
    __shared__ float As[64][33];   // +1 pad: scalar a-reads conflict-free
    __shared__ float Bs[32][128];  // float4-read, row-broadcast across lanes

    const int tid  = threadIdx.x;
    const int m0   = blockIdx.x * 64;
    const int col0 = (tid & 15) * 8;   // 16 col-groups x 8
    const int row0 = (tid >> 4) * 4;   // 16 row-groups x 4

    float acc[4][8];
#pragma unroll
    for (int i = 0; i < 4; ++i)
#pragma unroll
        for (int j = 0; j < 8; ++j) acc[i][j] = 0.f;

    for (int pass = 0; pass < 2; ++pass) {
        const float* __restrict__ A = pass ? msg : hin;
        const float* __restrict__ W = pass ? Wn : Ws;
        for (int kt = 0; kt < 4; ++kt) {
            const int k0 = kt * 32;
#pragma unroll
            for (int c = tid; c < 512; c += 256) {
                int r = c >> 3, kq = c & 7;
                int m = m0 + r;
                float4 v = make_float4(0.f, 0.f, 0.f, 0.f);
                if (m < N_NODES) v = *(const float4*)(A + (size_t)m * DIM + k0 + kq * 4);
                As[r][kq * 4 + 0] = v.x;
                As[r][kq * 4 + 1] = v.y;
                As[r][kq * 4 + 2] = v.z;
                As[r][kq * 4 + 3] = v.w;
            }
#pragma unroll
            for (int c = tid; c < 1024; c += 256) {
                int r = c >> 5, cq = c & 31;
                *(float4*)&Bs[r][cq * 4] = *(const float4*)(W + (size_t)(k0 + r) * DIM + cq * 4);
            }
            __syncthreads();
#pragma unroll
            for (int kk = 0; kk < 32; ++kk) {
                float a[4];
#pragma unroll
                for (int i = 0; i < 4; ++i) a[i] = As[row0 + i][kk];
                float4 b0 = *(const float4*)&Bs[kk][col0];
                float4 b1 = *(const float4*)&Bs[kk][col0 + 4];
                float bb[8] = {b0.x, b0.y, b0.z, b0.w, b1.x, b1.y, b1.z, b1.w};
#pragma unroll
                for (int i = 0; i < 4; ++i)
#pragma unroll
                    for (int j = 0; j < 8; ++j) acc[i][j] += a[i] * bb[j];
            }
            __syncthreads();
        }
    }
#pragma unroll
    for (int i = 0; i < 4; ++i) {
        int m = m0 + row0 + i;
        if (m < N_NODES) {
            float4 o0, o1;
            o0.x = fmaxf(acc[i][0] + bias[col0 + 0], 0.f);
            o0.y = fmaxf(acc[i][1] + bias[col0 + 1], 0.f);
            o0.z = fmaxf(acc[i][2] + bias[col0 + 2], 0.f);
            o0.w = fmaxf(acc[i][3] + bias[col0 + 3], 0.f);
            o1.x = fmaxf(acc[i][4] + bias[col0 + 4], 0.f);
            o1.y = fmaxf(acc[i][5] + bias[col0 + 5], 0.f);
            o1.z = fmaxf(acc[i][6] + bias[col0 + 6], 0.f);
            o1.w = fmaxf(acc[i][7] + bias[col0 + 7], 0.f);
            *(float4*)(hout + (size_t)m * DIM + col0)     = o0;
            *(float4*)(hout + (size_t)m * DIM + col0 + 4) = o1;
        }
    }
}

// ---------------- graph mean-pool (graph_ids sorted -> run-length accumulate) ----------------
__global__ __launch_bounds__(256) void k_pool(const float* __restrict__ h,
                                              const int* __restrict__ gid,
                                              float* __restrict__ pooled) {
    int d = threadIdx.x & 127;
    int half = threadIdx.x >> 7;
    int n0 = blockIdx.x * 128;
    float acc = 0.f;
    int cur = -1;
    for (int i = half; i < 128; i += 2) {
        int n = n0 + i;
        if (n >= N_NODES) break;
        int g = gid[n];
        if (g != cur) {
            if (cur >= 0) atomicAdd(&pooled[(size_t)cur * DIM + d], acc);
            acc = 0.f;
            cur = g;
        }
        acc += h[(size_t)n * DIM + d];
    }
    if (cur >= 0) atomicAdd(&pooled[(size_t)cur * DIM + d], acc);
}

// ---------------- classifier: out = (pooled/counts) @ Wf + bf ----------------
__global__ __launch_bounds__(256) void k_final(const float* __restrict__ pooled,
                                               const float* __restrict__ counts,
                                               const float* __restrict__ Wf,
                                               const float* __restrict__ bf,
                                               float* __restrict__ out) {
    int t = blockIdx.x * 256 + threadIdx.x;
    if (t >= N_GRAPHS * CLS) return;
    int g = t / CLS, c = t % CLS;
    float inv = 1.0f / fmaxf(counts[g], 1.0f);
    float s = 0.f;
    for (int k = 0; k < DIM; ++k) s += pooled[(size_t)g * DIM + k] * Wf[k * CLS + c];
    out[t] = s * inv + bf[c];
}

extern "C" void kernel_launch(void* const* d_in, const int* in_sizes, int n_in,
                              void* d_out, int out_size, void* d_ws, size_t ws_size,
                              hipStream_t stream) {
    const float* features = (const float*)d_in[0];
    const int*   esrc     = (const int*)d_in[1];
    const int*   edst     = (const int*)d_in[2];
    const int*   gids     = (const int*)d_in[3];
    const float* Wss[3] = {(const float*)d_in[4], (const float*)d_in[7], (const float*)d_in[10]};
    const float* Wns[3] = {(const float*)d_in[5], (const float*)d_in[8], (const float*)d_in[11]};
    const float* bs[3]  = {(const float*)d_in[6], (const float*)d_in[9], (const float*)d_in[12]};
    const float* Wf = (const float*)d_in[13];
    const float* bfv = (const float*)d_in[14];
    float* out = (float*)d_out;

    // workspace layout: ints first, then floats
    int* deg_i  = (int*)d_ws;            // 50048
    int* rowptr = deg_i + 50048;         // 50064 (50001 used)
    int* cursor = rowptr + 50064;        // 50048
    int* eidx   = cursor + 50048;        // 800000
    float* msg    = (float*)(eidx + 800000);          // 6.4M
    float* hA     = msg + (size_t)N_NODES * DIM;      // 6.4M
    float* hB     = hA  + (size_t)N_NODES * DIM;      // 6.4M
    float* pooled = hB  + (size_t)N_NODES * DIM;      // 16384
    float* counts = pooled + N_GRAPHS * DIM;          // 128

    hipMemsetAsync(deg_i, 0, 50048 * sizeof(int), stream);
    hipMemsetAsync(pooled, 0, N_GRAPHS * DIM * sizeof(float), stream);

    // CSR build (rebuilt each call per harness rules)
    k_deg_i<<<(N_EDGES + 255) / 256, 256, 0, stream>>>(edst, deg_i);
    k_count_sorted<<<1, 128, 0, stream>>>(gids, counts);
    k_scan<<<1, 256, 0, stream>>>(deg_i, rowptr);
    hipMemcpyAsync(cursor, rowptr, 50000 * sizeof(int), hipMemcpyDeviceToDevice, stream);
    k_fill<<<(N_EDGES + 255) / 256, 256, 0, stream>>>(esrc, edst, cursor, eidx);

    const float* hcur = features;
    float* houts[3] = {hA, hB, hA};
    for (int l = 0; l < 3; ++l) {
        k_gather<<<(N_NODES * 64 + 255) / 256, 256, 0, stream>>>(hcur, rowptr, eidx, msg);
        k_sage<<<(N_NODES + 63) / 64, 256, 0, stream>>>(hcur, msg, Wss[l], Wns[l], bs[l], houts[l]);
        hcur = houts[l];
    }

    k_pool<<<(N_NODES + 127) / 128, 256, 0, stream>>>(hcur, gids, pooled);
    k_final<<<(N_GRAPHS * CLS + 255) / 256, 256, 0, stream>>>(pooled, counts, Wf, bfv, out);
}

// Round 4
// 610.918 us; speedup vs baseline: 7.5816x; 1.2144x over previous
//
#include <hip/hip_runtime.h>

#define N_NODES  50000
#define N_EDGES  800000
#define N_GRAPHS 128
#define DIM      128
#define CLS      10
#define NB_SCAN  ((N_NODES + 255) / 256)   // 196

// ---------------- int degree count ----------------
__global__ __launch_bounds__(256) void k_deg_i(const int* __restrict__ dst, int* __restrict__ deg) {
    int i = blockIdx.x * 256 + threadIdx.x;
    if (i < N_EDGES) atomicAdd(&deg[dst[i]], 1);
}

// ---------------- graph counts via binary search (graph_ids sorted) ----------------
__global__ __launch_bounds__(128) void k_count_sorted(const int* __restrict__ gid, float* __restrict__ counts) {
    int g = threadIdx.x;
    int lo = 0, hi = N_NODES;
    while (lo < hi) { int mid = (lo + hi) >> 1; if (gid[mid] < g) lo = mid + 1; else hi = mid; }
    int start = lo;
    lo = 0; hi = N_NODES;
    while (lo < hi) { int mid = (lo + hi) >> 1; if (gid[mid] <= g) lo = mid + 1; else hi = mid; }
    counts[g] = (float)(lo - start);
}

// ---------------- parallel 3-phase scan ----------------
__global__ __launch_bounds__(256) void k_scan_part(const int* __restrict__ deg,
                                                   int* __restrict__ rowptr, int* __restrict__ bsum) {
    __shared__ int s[256];
    const int tid = threadIdx.x;
    const int i = blockIdx.x * 256 + tid;
    int v = (i < N_NODES) ? deg[i] : 0;
    s[tid] = v;
    __syncthreads();
    for (int off = 1; off < 256; off <<= 1) {
        int add = (tid >= off) ? s[tid - off] : 0;
        __syncthreads();
        s[tid] += add;
        __syncthreads();
    }
    if (i < N_NODES) rowptr[i] = s[tid] - v;   // local exclusive
    if (tid == 255) bsum[blockIdx.x] = s[255];
}

__global__ __launch_bounds__(256) void k_scan_top(const int* __restrict__ bsum, int* __restrict__ boff,
                                                  int* __restrict__ rowptr) {
    __shared__ int s[256];
    const int tid = threadIdx.x;
    int v = (tid < NB_SCAN) ? bsum[tid] : 0;
    s[tid] = v;
    __syncthreads();
    for (int off = 1; off < 256; off <<= 1) {
        int add = (tid >= off) ? s[tid - off] : 0;
        __syncthreads();
        s[tid] += add;
        __syncthreads();
    }
    if (tid < NB_SCAN) boff[tid] = s[tid] - v;  // exclusive block offsets
    if (tid == 0) rowptr[N_NODES] = N_EDGES;
}

__global__ __launch_bounds__(256) void k_scan_add(int* __restrict__ rowptr, const int* __restrict__ boff,
                                                  int* __restrict__ cursor) {
    const int i = blockIdx.x * 256 + threadIdx.x;
    if (i < N_NODES) {
        int r = rowptr[i] + boff[blockIdx.x];
        rowptr[i] = r;
        cursor[i] = r;
    }
}

// ---------------- CSR fill: cursor pre-loaded with rowptr ----------------
__global__ __launch_bounds__(256) void k_fill(const int* __restrict__ src, const int* __restrict__ dst,
                                              int* __restrict__ cursor, int* __restrict__ eidx) {
    int i = blockIdx.x * 256 + threadIdx.x;
    if (i < N_EDGES) {
        int pos = atomicAdd(&cursor[dst[i]], 1);
        eidx[pos] = src[i];
    }
}

// ---------------- gather aggregation: one wave per node ----------------
__global__ __launch_bounds__(256) void k_gather(const float* __restrict__ h,
                                                const int* __restrict__ rowptr,
                                                const int* __restrict__ eidx,
                                                float* __restrict__ msg) {
    const int wave = (blockIdx.x * 256 + threadIdx.x) >> 6;
    const int lane = threadIdx.x & 63;
    if (wave >= N_NODES) return;
    const int epar = lane >> 5;
    const int d0   = (lane & 31) * 4;
    const int beg = rowptr[wave], end = rowptr[wave + 1];
    float4 acc = make_float4(0.f, 0.f, 0.f, 0.f);
    for (int j = beg + epar; j < end; j += 2) {
        int s = eidx[j];
        float4 v = *(const float4*)(h + (size_t)s * DIM + d0);
        acc.x += v.x; acc.y += v.y; acc.z += v.z; acc.w += v.w;
    }
    acc.x += __shfl_xor(acc.x, 32);
    acc.y += __shfl_xor(acc.y, 32);
    acc.z += __shfl_xor(acc.z, 32);
    acc.w += __shfl_xor(acc.w, 32);
    if (epar == 0) {
        const float inv = (end > beg) ? 1.0f / (float)(end - beg) : 0.f;
        acc.x *= inv; acc.y *= inv; acc.z *= inv; acc.w *= inv;
        *(float4*)(msg + (size_t)wave * DIM + d0) = acc;
    }
}

// ---------------- fused SAGE layer: 128x128 tile, 8x8 acc/thread ----------------
// hout = relu(hin @ Ws + msg @ Wn + b)
__global__ __launch_bounds__(256) void k_sage(const float* __restrict__ hin,
                                              const float* __restrict__ msg,
                                              const float* __restrict__ Ws,
                                              const float* __restrict__ Wn,
                                              const float* __restrict__ bias,
                                              float* __restrict__ hout) {
    __shared__ float At[32][132];  // A-chunk transposed [k][m]; stride 132: 16B-aligned rows, a-reads broadcast
    __shared__ float Bs[32][128];  // b-reads split-col 2-way aliased = free

    const int tid  = threadIdx.x;
    const int m0   = blockIdx.x * 128;
    const int row0 = (tid >> 4) * 8;   // 16 row-groups x 8 rows
    const int c4   = (tid & 15) * 4;   // cols {c4..c4+3} and {c4+64..c4+67}

    float acc[8][8];
#pragma unroll
    for (int i = 0; i < 8; ++i)
#pragma unroll
        for (int j = 0; j < 8; ++j) acc[i][j] = 0.f;

#pragma unroll 1
    for (int pass = 0; pass < 2; ++pass) {
        const float* __restrict__ A = pass ? msg : hin;
        const float* __restrict__ W = pass ? Wn : Ws;
#pragma unroll 1
        for (int kt = 0; kt < 4; ++kt) {
            const int k0 = kt * 32;
            // stage A chunk transposed: 128 rows x 32 k  (4 float4 loads/thread)
#pragma unroll
            for (int i = 0; i < 4; ++i) {
                int idx = tid + i * 256;
                int m = idx >> 3, kq = idx & 7;
                int gm = m0 + m;
                float4 v = make_float4(0.f, 0.f, 0.f, 0.f);
                if (gm < N_NODES) v = *(const float4*)(A + (size_t)gm * DIM + k0 + kq * 4);
                At[kq * 4 + 0][m] = v.x;
                At[kq * 4 + 1][m] = v.y;
                At[kq * 4 + 2][m] = v.z;
                At[kq * 4 + 3][m] = v.w;
            }
            // stage B chunk: 32 k x 128 cols (4 float4 loads/thread)
#pragma unroll
            for (int i = 0; i < 4; ++i) {
                int idx = tid + i * 256;
                int r = idx >> 5, cq = idx & 31;
                *(float4*)&Bs[r][cq * 4] = *(const float4*)(W + (size_t)(k0 + r) * DIM + cq * 4);
            }
            __syncthreads();
#pragma unroll
            for (int kk = 0; kk < 32; ++kk) {
                float4 a0 = *(const float4*)&At[kk][row0];
                float4 a1 = *(const float4*)&At[kk][row0 + 4];
                float4 b0 = *(const float4*)&Bs[kk][c4];
                float4 b1 = *(const float4*)&Bs[kk][c4 + 64];
                float av[8] = {a0.x, a0.y, a0.z, a0.w, a1.x, a1.y, a1.z, a1.w};
                float bv[8] = {b0.x, b0.y, b0.z, b0.w, b1.x, b1.y, b1.z, b1.w};
#pragma unroll
                for (int i = 0; i < 8; ++i)
#pragma unroll
                    for (int j = 0; j < 8; ++j) acc[i][j] += av[i] * bv[j];
            }
            __syncthreads();
        }
    }
    // epilogue: bias + relu; two float4 stores per row
#pragma unroll
    for (int i = 0; i < 8; ++i) {
        int m = m0 + row0 + i;
        if (m < N_NODES) {
            float4 o0, o1;
            o0.x = fmaxf(acc[i][0] + bias[c4 + 0], 0.f);
            o0.y = fmaxf(acc[i][1] + bias[c4 + 1], 0.f);
            o0.z = fmaxf(acc[i][2] + bias[c4 + 2], 0.f);
            o0.w = fmaxf(acc[i][3] + bias[c4 + 3], 0.f);
            o1.x = fmaxf(acc[i][4] + bias[c4 + 64], 0.f);
            o1.y = fmaxf(acc[i][5] + bias[c4 + 65], 0.f);
            o1.z = fmaxf(acc[i][6] + bias[c4 + 66], 0.f);
            o1.w = fmaxf(acc[i][7] + bias[c4 + 67], 0.f);
            *(float4*)(hout + (size_t)m * DIM + c4)      = o0;
            *(float4*)(hout + (size_t)m * DIM + c4 + 64) = o1;
        }
    }
}

// ---------------- graph mean-pool ----------------
__global__ __launch_bounds__(256) void k_pool(const float* __restrict__ h,
                                              const int* __restrict__ gid,
                                              float* __restrict__ pooled) {
    int d = threadIdx.x & 127;
    int half = threadIdx.x >> 7;
    int n0 = blockIdx.x * 128;
    float acc = 0.f;
    int cur = -1;
    for (int i = half; i < 128; i += 2) {
        int n = n0 + i;
        if (n >= N_NODES) break;
        int g = gid[n];
        if (g != cur) {
            if (cur >= 0) atomicAdd(&pooled[(size_t)cur * DIM + d], acc);
            acc = 0.f;
            cur = g;
        }
        acc += h[(size_t)n * DIM + d];
    }
    if (cur >= 0) atomicAdd(&pooled[(size_t)cur * DIM + d], acc);
}

// ---------------- classifier ----------------
__global__ __launch_bounds__(256) void k_final(const float* __restrict__ pooled,
                                               const float* __restrict__ counts,
                                               const float* __restrict__ Wf,
                                               const float* __restrict__ bf,
                                               float* __restrict__ out) {
    int t = blockIdx.x * 256 + threadIdx.x;
    if (t >= N_GRAPHS * CLS) return;
    int g = t / CLS, c = t % CLS;
    float inv = 1.0f / fmaxf(counts[g], 1.0f);
    float s = 0.f;
    for (int k = 0; k < DIM; ++k) s += pooled[(size_t)g * DIM + k] * Wf[k * CLS + c];
    out[t] = s * inv + bf[c];
}

extern "C" void kernel_launch(void* const* d_in, const int* in_sizes, int n_in,
                              void* d_out, int out_size, void* d_ws, size_t ws_size,
                              hipStream_t stream) {
    const float* features = (const float*)d_in[0];
    const int*   esrc     = (const int*)d_in[1];
    const int*   edst     = (const int*)d_in[2];
    const int*   gids     = (const int*)d_in[3];
    const float* Wss[3] = {(const float*)d_in[4], (const float*)d_in[7], (const float*)d_in[10]};
    const float* Wns[3] = {(const float*)d_in[5], (const float*)d_in[8], (const float*)d_in[11]};
    const float* bs[3]  = {(const float*)d_in[6], (const float*)d_in[9], (const float*)d_in[12]};
    const float* Wf = (const float*)d_in[13];
    const float* bfv = (const float*)d_in[14];
    float* out = (float*)d_out;

    // workspace layout
    int* deg_i  = (int*)d_ws;            // 50048
    int* rowptr = deg_i + 50048;         // 50064 (50001 used)
    int* cursor = rowptr + 50064;        // 50048
    int* bsum   = cursor + 50048;        // 256
    int* boff   = bsum + 256;            // 256
    int* eidx   = boff + 256;            // 800000
    float* msg    = (float*)(eidx + 800000);
    float* hA     = msg + (size_t)N_NODES * DIM;
    float* hB     = hA  + (size_t)N_NODES * DIM;
    float* pooled = hB  + (size_t)N_NODES * DIM;
    float* counts = pooled + N_GRAPHS * DIM;

    hipMemsetAsync(deg_i, 0, 50048 * sizeof(int), stream);
    hipMemsetAsync(pooled, 0, N_GRAPHS * DIM * sizeof(float), stream);

    // CSR build
    k_deg_i<<<(N_EDGES + 255) / 256, 256, 0, stream>>>(edst, deg_i);
    k_count_sorted<<<1, 128, 0, stream>>>(gids, counts);
    k_scan_part<<<NB_SCAN, 256, 0, stream>>>(deg_i, rowptr, bsum);
    k_scan_top<<<1, 256, 0, stream>>>(bsum, boff, rowptr);
    k_scan_add<<<NB_SCAN, 256, 0, stream>>>(rowptr, boff, cursor);
    k_fill<<<(N_EDGES + 255) / 256, 256, 0, stream>>>(esrc, edst, cursor, eidx);

    const float* hcur = features;
    float* houts[3] = {hA, hB, hA};
    for (int l = 0; l < 3; ++l) {
        k_gather<<<(N_NODES * 64 + 255) / 256, 256, 0, stream>>>(hcur, rowptr, eidx, msg);
        k_sage<<<(N_NODES + 127) / 128, 256, 0, stream>>>(hcur, msg, Wss[l], Wns[l], bs[l], houts[l]);
        hcur = houts[l];
    }

    k_pool<<<(N_NODES + 127) / 128, 256, 0, stream>>>(hcur, gids, pooled);
    k_final<<<(N_GRAPHS * CLS + 255) / 256, 256, 0, stream>>>(pooled, counts, Wf, bfv, out);
}

// Round 5
// 419.814 us; speedup vs baseline: 11.0328x; 1.4552x over previous
//
#include <hip/hip_runtime.h>

#define N_NODES  50000
#define N_EDGES  800000
#define N_GRAPHS 128
#define DIM      128
#define K2       256
#define CLS      10
#define NB_SCAN  ((N_NODES + 255) / 256)   // 196

typedef __attribute__((ext_vector_type(8))) short bf16x8;
typedef __attribute__((ext_vector_type(4))) float f32x4;

__device__ inline unsigned short f2bf(float f) {
    unsigned u = __float_as_uint(f);
    unsigned r = (u + 0x7FFFu + ((u >> 16) & 1u)) >> 16;   // RNE
    return (unsigned short)r;
}
__device__ inline float bf2f(unsigned short s) {
    return __uint_as_float(((unsigned)s) << 16);
}

// ---------------- int degree count ----------------
__global__ __launch_bounds__(256) void k_deg_i(const int* __restrict__ dst, int* __restrict__ deg) {
    int i = blockIdx.x * 256 + threadIdx.x;
    if (i < N_EDGES) atomicAdd(&deg[dst[i]], 1);
}

// ---------------- graph counts via binary search (graph_ids sorted) ----------------
__global__ __launch_bounds__(128) void k_count_sorted(const int* __restrict__ gid, float* __restrict__ counts) {
    int g = threadIdx.x;
    int lo = 0, hi = N_NODES;
    while (lo < hi) { int mid = (lo + hi) >> 1; if (gid[mid] < g) lo = mid + 1; else hi = mid; }
    int start = lo;
    lo = 0; hi = N_NODES;
    while (lo < hi) { int mid = (lo + hi) >> 1; if (gid[mid] <= g) lo = mid + 1; else hi = mid; }
    counts[g] = (float)(lo - start);
}

// ---------------- parallel 3-phase scan ----------------
__global__ __launch_bounds__(256) void k_scan_part(const int* __restrict__ deg,
                                                   int* __restrict__ rowptr, int* __restrict__ bsum) {
    __shared__ int s[256];
    const int tid = threadIdx.x;
    const int i = blockIdx.x * 256 + tid;
    int v = (i < N_NODES) ? deg[i] : 0;
    s[tid] = v;
    __syncthreads();
    for (int off = 1; off < 256; off <<= 1) {
        int add = (tid >= off) ? s[tid - off] : 0;
        __syncthreads();
        s[tid] += add;
        __syncthreads();
    }
    if (i < N_NODES) rowptr[i] = s[tid] - v;
    if (tid == 255) bsum[blockIdx.x] = s[255];
}

__global__ __launch_bounds__(256) void k_scan_top(const int* __restrict__ bsum, int* __restrict__ boff,
                                                  int* __restrict__ rowptr) {
    __shared__ int s[256];
    const int tid = threadIdx.x;
    int v = (tid < NB_SCAN) ? bsum[tid] : 0;
    s[tid] = v;
    __syncthreads();
    for (int off = 1; off < 256; off <<= 1) {
        int add = (tid >= off) ? s[tid - off] : 0;
        __syncthreads();
        s[tid] += add;
        __syncthreads();
    }
    if (tid < NB_SCAN) boff[tid] = s[tid] - v;
    if (tid == 0) rowptr[N_NODES] = N_EDGES;
}

__global__ __launch_bounds__(256) void k_scan_add(int* __restrict__ rowptr, const int* __restrict__ boff,
                                                  int* __restrict__ cursor) {
    const int i = blockIdx.x * 256 + threadIdx.x;
    if (i < N_NODES) {
        int r = rowptr[i] + boff[blockIdx.x];
        rowptr[i] = r;
        cursor[i] = r;
    }
}

// ---------------- CSR fill ----------------
__global__ __launch_bounds__(256) void k_fill(const int* __restrict__ src, const int* __restrict__ dst,
                                              int* __restrict__ cursor, int* __restrict__ eidx) {
    int i = blockIdx.x * 256 + threadIdx.x;
    if (i < N_EDGES) {
        int pos = atomicAdd(&cursor[dst[i]], 1);
        eidx[pos] = src[i];
    }
}

// ---------------- features fp32 -> bf16 hcat0 h-part ----------------
__global__ __launch_bounds__(256) void k_cast(const float* __restrict__ f, unsigned short* __restrict__ c0) {
    int t = blockIdx.x * 256 + threadIdx.x;   // one per 8 elems
    if (t >= N_NODES * 16) return;
    int row = t >> 4, c8 = (t & 15) * 8;
    const float* p = f + (size_t)row * DIM + c8;
    float4 a = *(const float4*)p;
    float4 b = *(const float4*)(p + 4);
    uint4 v;
    v.x = f2bf(a.x) | ((unsigned)f2bf(a.y) << 16);
    v.y = f2bf(a.z) | ((unsigned)f2bf(a.w) << 16);
    v.z = f2bf(b.x) | ((unsigned)f2bf(b.y) << 16);
    v.w = f2bf(b.z) | ((unsigned)f2bf(b.w) << 16);
    *(uint4*)(c0 + (size_t)row * K2 + c8) = v;
}

// ---------------- weights: transpose + concat + hi/lo split -> Wt[l][n][k0..255] ----------------
__global__ __launch_bounds__(256) void k_prep_w(const float* __restrict__ Ws0, const float* __restrict__ Wn0,
                                                const float* __restrict__ Ws1, const float* __restrict__ Wn1,
                                                const float* __restrict__ Ws2, const float* __restrict__ Wn2,
                                                unsigned short* __restrict__ hi, unsigned short* __restrict__ lo) {
    int t = blockIdx.x * 256 + threadIdx.x;
    if (t >= 3 * DIM * K2) return;
    int l = t / (DIM * K2), r = t % (DIM * K2);
    int n = r / K2, k = r % K2;
    const float* Ws = (l == 0) ? Ws0 : (l == 1) ? Ws1 : Ws2;
    const float* Wn = (l == 0) ? Wn0 : (l == 1) ? Wn1 : Wn2;
    float w = (k < DIM) ? Ws[k * DIM + n] : Wn[(k - DIM) * DIM + n];
    unsigned short h = f2bf(w);
    hi[t] = h;
    lo[t] = f2bf(w - bf2f(h));
}

// ---------------- gather: one wave per node, bf16 rows, fp32 accum ----------------
__global__ __launch_bounds__(256) void k_gather(const unsigned short* __restrict__ h,
                                                const int* __restrict__ rowptr,
                                                const int* __restrict__ eidx,
                                                unsigned short* __restrict__ msg) {
    const int node = (blockIdx.x * 256 + threadIdx.x) >> 6;
    const int lane = threadIdx.x & 63;
    if (node >= N_NODES) return;
    const int epar = lane >> 4;        // 4 edges in flight
    const int d0 = (lane & 15) * 8;    // 8 bf16 per lane = 16 B
    const int beg = rowptr[node], end = rowptr[node + 1];
    float acc[8] = {0.f, 0.f, 0.f, 0.f, 0.f, 0.f, 0.f, 0.f};
    for (int j = beg + epar; j < end; j += 4) {
        int s = eidx[j];
        uint4 v = *(const uint4*)(h + (size_t)s * K2 + d0);
        unsigned u[4] = {v.x, v.y, v.z, v.w};
#pragma unroll
        for (int i = 0; i < 4; ++i) {
            acc[2 * i]     += __uint_as_float(u[i] << 16);
            acc[2 * i + 1] += __uint_as_float(u[i] & 0xFFFF0000u);
        }
    }
#pragma unroll
    for (int i = 0; i < 8; ++i) {
        acc[i] += __shfl_xor(acc[i], 16);
        acc[i] += __shfl_xor(acc[i], 32);
    }
    if (epar == 0) {
        float inv = (end > beg) ? 1.0f / (float)(end - beg) : 0.f;
        unsigned short o[8];
#pragma unroll
        for (int i = 0; i < 8; ++i) o[i] = f2bf(acc[i] * inv);
        uint4 v;
        v.x = o[0] | ((unsigned)o[1] << 16);
        v.y = o[2] | ((unsigned)o[3] << 16);
        v.z = o[4] | ((unsigned)o[5] << 16);
        v.w = o[6] | ((unsigned)o[7] << 16);
        *(uint4*)(msg + (size_t)node * K2 + DIM + d0) = v;
    }
}

// ---------------- SAGE layer: bf16 MFMA, single K=256 GEMM ----------------
// hout_h = relu(hcat @ [Ws;Wn] + b); W pre-split hi+lo to kill systematic bf16 weight error.
// Operand swap: A_op=W-frag, B_op=node-frag -> lane's D regs = 4 consecutive cols of one row.
__global__ __launch_bounds__(256) void k_sage(const unsigned short* __restrict__ hin,  // [m][256]
                                              const unsigned short* __restrict__ whi,  // [n][256]
                                              const unsigned short* __restrict__ wlo,
                                              const float* __restrict__ bias,
                                              unsigned short* __restrict__ hout) {
    __shared__ unsigned short Ah[128 * 40];   // node rows,  stride 40 shorts (80 B): 2-way bank alias = free
    __shared__ unsigned short Bh[128 * 40];   // W hi rows
    __shared__ unsigned short Bl[128 * 40];   // W lo rows
    const int tid = threadIdx.x;
    const int wv = tid >> 6, lane = tid & 63;
    const int m0 = blockIdx.x * 128;
    const int m_off = (wv >> 1) * 64, n_off = (wv & 1) * 64;
    const int l15 = lane & 15, q = lane >> 4;

    f32x4 acc[4][4];
#pragma unroll
    for (int a = 0; a < 4; ++a)
#pragma unroll
        for (int b = 0; b < 4; ++b) acc[a][b] = (f32x4){0.f, 0.f, 0.f, 0.f};

#pragma unroll 1
    for (int kt = 0; kt < 8; ++kt) {
        const int k0 = kt * 32;
#pragma unroll
        for (int i = 0; i < 2; ++i) {
            int idx = tid + i * 256;
            int row = idx >> 2, kq = (idx & 3) * 8;
            int gm = m0 + row;
            uint4 va = make_uint4(0u, 0u, 0u, 0u);
            if (gm < N_NODES) va = *(const uint4*)(hin + (size_t)gm * K2 + k0 + kq);
            *(uint4*)&Ah[row * 40 + kq] = va;
            *(uint4*)&Bh[row * 40 + kq] = *(const uint4*)(whi + (size_t)row * K2 + k0 + kq);
            *(uint4*)&Bl[row * 40 + kq] = *(const uint4*)(wlo + (size_t)row * K2 + k0 + kq);
        }
        __syncthreads();
        bf16x8 hf[4], wh[4], wl[4];
#pragma unroll
        for (int mt = 0; mt < 4; ++mt)
            hf[mt] = *(const bf16x8*)&Ah[(m_off + mt * 16 + l15) * 40 + q * 8];
#pragma unroll
        for (int nt = 0; nt < 4; ++nt) {
            wh[nt] = *(const bf16x8*)&Bh[(n_off + nt * 16 + l15) * 40 + q * 8];
            wl[nt] = *(const bf16x8*)&Bl[(n_off + nt * 16 + l15) * 40 + q * 8];
        }
#pragma unroll
        for (int mt = 0; mt < 4; ++mt)
#pragma unroll
            for (int nt = 0; nt < 4; ++nt) {
                acc[mt][nt] = __builtin_amdgcn_mfma_f32_16x16x32_bf16(wh[nt], hf[mt], acc[mt][nt], 0, 0, 0);
                acc[mt][nt] = __builtin_amdgcn_mfma_f32_16x16x32_bf16(wl[nt], hf[mt], acc[mt][nt], 0, 0, 0);
            }
        __syncthreads();
    }
    // epilogue: lane holds row m = l15 (per mt), cols n..n+3 = consecutive -> 8 B stores
#pragma unroll
    for (int nt = 0; nt < 4; ++nt) {
        int n = n_off + nt * 16 + q * 4;
        float4 bv = *(const float4*)(bias + n);
#pragma unroll
        for (int mt = 0; mt < 4; ++mt) {
            int m = m0 + m_off + mt * 16 + l15;
            if (m < N_NODES) {
                f32x4 a = acc[mt][nt];
                unsigned short o0 = f2bf(fmaxf(a[0] + bv.x, 0.f));
                unsigned short o1 = f2bf(fmaxf(a[1] + bv.y, 0.f));
                unsigned short o2 = f2bf(fmaxf(a[2] + bv.z, 0.f));
                unsigned short o3 = f2bf(fmaxf(a[3] + bv.w, 0.f));
                uint2 v;
                v.x = o0 | ((unsigned)o1 << 16);
                v.y = o2 | ((unsigned)o3 << 16);
                *(uint2*)(hout + (size_t)m * K2 + n) = v;
            }
        }
    }
}

// ---------------- graph mean-pool (bf16 h, sorted gids) ----------------
__global__ __launch_bounds__(256) void k_pool(const unsigned short* __restrict__ h,
                                              const int* __restrict__ gid,
                                              float* __restrict__ pooled) {
    int d = threadIdx.x & 127;
    int half = threadIdx.x >> 7;
    int n0 = blockIdx.x * 128;
    float acc = 0.f;
    int cur = -1;
    for (int i = half; i < 128; i += 2) {
        int n = n0 + i;
        if (n >= N_NODES) break;
        int g = gid[n];
        if (g != cur) {
            if (cur >= 0) atomicAdd(&pooled[(size_t)cur * DIM + d], acc);
            acc = 0.f;
            cur = g;
        }
        acc += bf2f(h[(size_t)n * K2 + d]);
    }
    if (cur >= 0) atomicAdd(&pooled[(size_t)cur * DIM + d], acc);
}

// ---------------- classifier (fp32) ----------------
__global__ __launch_bounds__(256) void k_final(const float* __restrict__ pooled,
                                               const float* __restrict__ counts,
                                               const float* __restrict__ Wf,
                                               const float* __restrict__ bf,
                                               float* __restrict__ out) {
    int t = blockIdx.x * 256 + threadIdx.x;
    if (t >= N_GRAPHS * CLS) return;
    int g = t / CLS, c = t % CLS;
    float inv = 1.0f / fmaxf(counts[g], 1.0f);
    float s = 0.f;
    for (int k = 0; k < DIM; ++k) s += pooled[(size_t)g * DIM + k] * Wf[k * CLS + c];
    out[t] = s * inv + bf[c];
}

extern "C" void kernel_launch(void* const* d_in, const int* in_sizes, int n_in,
                              void* d_out, int out_size, void* d_ws, size_t ws_size,
                              hipStream_t stream) {
    const float* features = (const float*)d_in[0];
    const int*   esrc     = (const int*)d_in[1];
    const int*   edst     = (const int*)d_in[2];
    const int*   gids     = (const int*)d_in[3];
    const float* bs[3]  = {(const float*)d_in[6], (const float*)d_in[9], (const float*)d_in[12]};
    const float* Wf = (const float*)d_in[13];
    const float* bfv = (const float*)d_in[14];
    float* out = (float*)d_out;

    // ---- workspace layout ----
    int* deg_i  = (int*)d_ws;            // 50048
    int* rowptr = deg_i + 50048;         // 50064
    int* cursor = rowptr + 50064;        // 50048
    int* bsum   = cursor + 50048;        // 256
    int* boff   = bsum + 256;            // 256
    int* eidx   = boff + 256;            // 800000
    float* pooled = (float*)(eidx + 800000);     // 16384
    float* counts = pooled + N_GRAPHS * DIM;     // 128
    unsigned short* C0  = (unsigned short*)(counts + 128);        // 50000*256 bf16
    unsigned short* C1  = C0 + (size_t)N_NODES * K2;
    unsigned short* C2  = C1 + (size_t)N_NODES * K2;
    unsigned short* Whi = C2 + (size_t)N_NODES * K2;              // 3*128*256
    unsigned short* Wlo = Whi + 3 * DIM * K2;
    // total ~81.1 MB

    hipMemsetAsync(deg_i, 0, 50048 * sizeof(int), stream);
    hipMemsetAsync(pooled, 0, N_GRAPHS * DIM * sizeof(float), stream);

    // CSR build + precompute
    k_deg_i<<<(N_EDGES + 255) / 256, 256, 0, stream>>>(edst, deg_i);
    k_count_sorted<<<1, 128, 0, stream>>>(gids, counts);
    k_scan_part<<<NB_SCAN, 256, 0, stream>>>(deg_i, rowptr, bsum);
    k_scan_top<<<1, 256, 0, stream>>>(bsum, boff, rowptr);
    k_scan_add<<<NB_SCAN, 256, 0, stream>>>(rowptr, boff, cursor);
    k_fill<<<(N_EDGES + 255) / 256, 256, 0, stream>>>(esrc, edst, cursor, eidx);
    k_cast<<<(N_NODES * 16 + 255) / 256, 256, 0, stream>>>(features, C0);
    k_prep_w<<<(3 * DIM * K2 + 255) / 256, 256, 0, stream>>>(
        (const float*)d_in[4], (const float*)d_in[5],
        (const float*)d_in[7], (const float*)d_in[8],
        (const float*)d_in[10], (const float*)d_in[11], Whi, Wlo);

    unsigned short* C[4] = {C0, C1, C2, C0};
    for (int l = 0; l < 3; ++l) {
        k_gather<<<(N_NODES * 64 + 255) / 256, 256, 0, stream>>>(C[l], rowptr, eidx, C[l]);
        k_sage<<<(N_NODES + 127) / 128, 256, 0, stream>>>(
            C[l], Whi + (size_t)l * DIM * K2, Wlo + (size_t)l * DIM * K2, bs[l], C[l + 1]);
    }

    k_pool<<<(N_NODES + 127) / 128, 256, 0, stream>>>(C0, gids, pooled);
    k_final<<<(N_GRAPHS * CLS + 255) / 256, 256, 0, stream>>>(pooled, counts, Wf, bfv, out);
}